// Round 11
// baseline (84.473 us; speedup 1.0000x reference)
//
#include <hip/hip_runtime.h>

#define MAX_SPIKE 100000.0f

constexpr int BATCH = 128;
constexpr int NIN   = 1024;
constexpr int MOUT  = 512;
constexpr int WIN   = 32;      // elements per staged window
constexpr int ROWS  = 1056;    // padded row stride for xs/ro (64-wide loads stay in-row)
constexpr int SPLIT = 768;     // seg0 screens [0,768), seg1 prefixes then screens [768,1024)
constexpr int ST    = 512;     // sort threads

typedef unsigned long long u64;
typedef unsigned int u32;

__device__ __forceinline__ void gll4(const void* g, void* l) {
    __builtin_amdgcn_global_load_lds((const __attribute__((address_space(1))) u32*)g,
                                     (__attribute__((address_space(3))) u32*)l, 4, 0, 0);
}
__device__ __forceinline__ float rlf(float v, int u) {
    return __uint_as_float((u32)__builtin_amdgcn_readlane((int)__float_as_uint(v), u));
}

// ---------------- kernel 1: per-row stable argsort (hybrid bitonic) --------
__global__ __launch_bounds__(ST) void snn_sort_kernel(const float* __restrict__ x,
                                                      float* __restrict__ xs_g,
                                                      int* __restrict__ ro_g) {
    __shared__ u64 keys[NIN];
    const int tid = threadIdx.x;
    const int b   = blockIdx.x;
    const int wv  = tid >> 6;
    const int l   = tid & 63;
    const int i0  = wv * 128 + l;     // bit6 == 0 always
    const int i1  = i0 + 64;

    // key = (float_bits << 32) | index: x >= 0 so uint order == float order;
    // index low bits make keys distinct -> deterministic == stable argsort.
    u64 e0 = ((u64)__float_as_uint(x[b * NIN + i0]) << 32) | (unsigned)i0;
    u64 e1 = ((u64)__float_as_uint(x[b * NIN + i1]) << 32) | (unsigned)i1;

    auto CE_SHFL = [&](u64& e, int idx, int k, int j) {
        u64 p = __shfl_xor(e, j, 64);
        bool lower   = ((l & j) == 0);
        bool asc     = ((idx & k) == 0);
        bool takeMin = (lower == asc);
        bool pLess   = (p < e);
        e = (pLess == takeMin) ? p : e;
    };
    auto CE_J64 = [&](int k) {
        bool asc = ((i0 & k) == 0);
        bool sw  = asc ? (e0 > e1) : (e0 < e1);
        if (sw) { u64 t = e0; e0 = e1; e1 = t; }
    };

    for (int k = 2; k <= 64; k <<= 1)
        for (int j = k >> 1; j >= 1; j >>= 1) { CE_SHFL(e0, i0, k, j); CE_SHFL(e1, i1, k, j); }
    CE_J64(128);
    for (int j = 32; j >= 1; j >>= 1) { CE_SHFL(e0, i0, 128, j); CE_SHFL(e1, i1, 128, j); }

    for (int k = 256; k <= NIN; k <<= 1) {
        keys[i0] = e0; keys[i1] = e1;
        __syncthreads();
        for (int j = k >> 1; j >= 128; j >>= 1) {
            int idx  = ((tid & ~(j - 1)) << 1) | (tid & (j - 1));
            int part = idx | j;
            u64 a = keys[idx], c = keys[part];
            bool asc = ((idx & k) == 0);
            if (asc ? (a > c) : (a < c)) { keys[idx] = c; keys[part] = a; }
            __syncthreads();
        }
        e0 = keys[i0]; e1 = keys[i1];
        CE_J64(k);
        for (int j = 32; j >= 1; j >>= 1) { CE_SHFL(e0, i0, k, j); CE_SHFL(e1, i1, k, j); }
    }

    xs_g[b * ROWS + i0] = __uint_as_float((unsigned)(e0 >> 32));
    xs_g[b * ROWS + i1] = __uint_as_float((unsigned)(e1 >> 32));
    ro_g[b * ROWS + i0] = (int)(unsigned)(e0 & 0xFFFFFFFFull) * (MOUT * 4);  // byte off
    ro_g[b * ROWS + i1] = (int)(unsigned)(e1 & 0xFFFFFFFFull) * (MOUT * 4);
    if (tid == 0) xs_g[b * ROWS + NIN] = MAX_SPIKE;
}

// ---------------- kernel 2: staged-window scan -----------------------------
// Per wave: weights DMA'd into wave-private LDS dbuf via global_load_lds
// (uniform base + lane*4 -- exactly the HW pattern); ro/xs via 64-wide
// coalesced register loads + readlane (addresses go SALU; xs is an SGPR
// operand). Buffer-ready is enforced by dataflow: each STAGE's readlane
// waits on a NEWER vmem load, draining all OLDER glls (vmcnt semantics),
// plus sched_barrier fences; explicit vmcnt(0) only at the tail.
__global__ __launch_bounds__(128) void snn_scan_kernel(const float* __restrict__ w,
                                                       const float* __restrict__ xs_g,
                                                       const int* __restrict__ ro_g,
                                                       float* __restrict__ out) {
    // Cumsums + exact path must match numpy f32: no implicit FMA contraction.
    // (explicit fmaf appears only in the CONSERVATIVE screen, margin-covered)
    #pragma clang fp contract(off)

    __shared__ float wbuf[2][2][WIN * 64];   // [wave][buf][elem*64 + lane]
    __shared__ float bestsh[2][64];

    const int tid  = threadIdx.x;
    const int b    = blockIdx.x >> 3;
    const int cg   = blockIdx.x & 7;
    const int wave = tid >> 6;
    const int lane = tid & 63;
    const int seg  = wave;
    const unsigned mo4 = (unsigned)(cg * 64 + lane) * 4u;

    const char*  wb  = (const char*)w;
    const int*   rop = ro_g + b * ROWS;
    const float* xsp = xs_g + b * ROWS;

    const int NWIN = seg ? (NIN / WIN) : (SPLIT / WIN);   // 32 : 24
    const int PREW = seg ? (SPLIT / WIN) : 0;             // 24 : 0

    float* bufA = &wbuf[wave][0][0];
    float* bufB = &wbuf[wave][1][0];

    float wcum = 0.0f, wicum = 0.0f, best = MAX_SPIKE;
    bool scr = false;

#define STAGE(BUF, ROV) { _Pragma("unroll") \
    for (int u = 0; u < WIN; ++u) { \
        unsigned sro = (unsigned)__builtin_amdgcn_readlane(ROV, u); \
        gll4(wb + (sro + mo4), &BUF[u * 64]); } }

#define CHEAP32(BUF, XSV) { _Pragma("unroll") \
    for (int u = 0; u < WIN; ++u) { \
        float ww = BUF[u * 64 + lane]; \
        float xv = rlf(XSV, u); \
        wcum  = wcum + ww; \
        wicum = wicum + ww * xv; } }   /* round mul, then add (np order) */

    // Screen: skip only when exact path PROVABLY rejects (q = RN(wi/d)):
    //   q < xv guaranteed if xv*d - wi > wi*2^-24 ; q > xl if wi - xl*d > wi*2^-24
    // thr = wi*2.4e-7 (~4 ulp, conservative). Borderline lanes take the exact
    // IEEE-division reference path. xl = rlf(XSV, u+1): lane 32 holds xs[base+32].
#define SCREEN32(BUF, XSV) { _Pragma("unroll") \
    for (int u = 0; u < WIN; ++u) { \
        float ww = BUF[u * 64 + lane]; \
        float xv = rlf(XSV, u); \
        float xl = rlf(XSV, u + 1); \
        wcum  = wcum + ww; \
        wicum = wicum + ww * xv; \
        float d   = fmaxf(wcum - 1.0f, 1e-10f); /* 1e10 clip never binds: wcum<=~5 */ \
        float thr = wicum * 2.4e-7f; \
        float lo  = fmaf(xv, d, -wicum); \
        float hi  = fmaf(xl, d, -wicum); \
        bool pot = (wcum >= 1.0f) && (lo <= thr) && (hi >= -thr); \
        if (pot) { \
            float q = wicum / d;              /* IEEE f32 div (matches np) */ \
            float cand = (q < xv || q > xl) ? MAX_SPIKE : q; \
            best = fminf(best, cand); \
        } } }

    // Cheap mode while ALL lanes have wcum < 1 (weights >= 0 -> monotone ->
    // reference emits MAX_SPIKE exactly). Crossing window is REPLAYED from a
    // 2-register snapshot (identical add order => bit-exact).
#define PROC32(BUF, XSV) { \
    if (!scr) { \
        float wc0 = wcum, wi0 = wicum; \
        CHEAP32(BUF, XSV); \
        if (__any((int)(wcum >= 1.0f))) { wcum = wc0; wicum = wi0; scr = true; } \
    } \
    if (scr) { SCREEN32(BUF, XSV); } }

    // prologue: ro/xs for windows 0,1; stage window 0
    int   roA = rop[lane];
    float xsA = xsp[lane];
    int   roB = rop[WIN + lane];
    float xsB = xsp[WIN + lane];
    STAGE(bufA, roA);
    __builtin_amdgcn_sched_barrier(0);

    for (int t = 0; t < NWIN; t += 2) {
        // ---- half 1: stage t+1 (B), compute t (A), prefetch t+2 ----
        STAGE(bufB, roB);                 // readlane(roB) drains older glls(t)
        __builtin_amdgcn_sched_barrier(0);
        if (t + 2 < NWIN) roA = rop[(t + 2) * WIN + lane];   // ro early: used next half
        if (t == PREW) scr = (__any((int)(wcum >= 1.0f)) != 0);
        if (t < PREW) { CHEAP32(bufA, xsA); } else { PROC32(bufA, xsA); }
        if (t + 2 < NWIN) xsA = xsp[(t + 2) * WIN + lane];   // xs late: used next iter
        __builtin_amdgcn_sched_barrier(0);

        // ---- half 2: stage t+2 (A), compute t+1 (B), prefetch t+3 ----
        if (t + 2 < NWIN) { STAGE(bufA, roA); }              // drains glls(t+1)
        else { asm volatile("s_waitcnt vmcnt(0)" ::: "memory"); }
        __builtin_amdgcn_sched_barrier(0);
        if (t + 3 < NWIN) roB = rop[(t + 3) * WIN + lane];
        if (t + 1 < PREW) { CHEAP32(bufB, xsB); } else { PROC32(bufB, xsB); }
        if (t + 3 < NWIN) xsB = xsp[(t + 3) * WIN + lane];
        __builtin_amdgcn_sched_barrier(0);
    }
#undef PROC32
#undef SCREEN32
#undef CHEAP32
#undef STAGE

    bestsh[wave][lane] = best;
    __syncthreads();
    if (tid < 64)
        out[b * MOUT + cg * 64 + tid] = fminf(bestsh[0][tid], bestsh[1][tid]);
}

// ---------------- fallback: fused kernel (if ws too small) -----------------
__global__ __launch_bounds__(256) void snn_fc_fused(const float* __restrict__ x,
                                                    const float* __restrict__ w,
                                                    float* __restrict__ out) {
    #pragma clang fp contract(off)
    __shared__ u64 keys[NIN];
    __shared__ float xs[NIN + 1];
    __shared__ int   roff[NIN];
    __shared__ float bestsh[4][64];

    const int tid  = threadIdx.x;
    const int b    = blockIdx.x >> 3;
    const int cg   = blockIdx.x & 7;
    const int wave = tid >> 6;
    const int lane = tid & 63;
    const int mo   = cg * 64 + lane;

    for (int i = tid; i < NIN; i += 256) {
        unsigned int bits = __float_as_uint(x[b * NIN + i]);
        keys[i] = ((u64)bits << 32) | (unsigned int)i;
    }
    __syncthreads();
    for (int k = 2; k <= NIN; k <<= 1)
        for (int j = k >> 1; j > 0; j >>= 1) {
            #pragma unroll
            for (int r = 0; r < NIN / 256; ++r) {
                int i = tid + r * 256, ixj = i ^ j;
                if (ixj > i) {
                    u64 a = keys[i], c2 = keys[ixj];
                    bool asc = ((i & k) == 0);
                    if ((a > c2) == asc) { keys[i] = c2; keys[ixj] = a; }
                }
            }
            __syncthreads();
        }
    for (int i = tid; i < NIN; i += 256) {
        u64 kk = keys[i];
        xs[i]   = __uint_as_float((unsigned int)(kk >> 32));
        roff[i] = (int)(kk & 0xFFFFFFFFull) * MOUT;
    }
    if (tid == 0) xs[NIN] = MAX_SPIKE;
    __syncthreads();

    const float* __restrict__ wcol = w + mo;
    float wcum = 0.0f, wicum = 0.0f, best = MAX_SPIKE;

    for (int n = 0; n < wave * 256; ++n) {
        float ww = wcol[roff[n]];
        wcum = wcum + ww;
        wicum = wicum + ww * xs[n];
    }
    const int n0 = wave * 256;
    float xprev = xs[n0];
    for (int n = n0; n < n0 + 256; ++n) {
        float ww = wcol[roff[n]];
        float xv = xprev, xl = xs[n + 1];
        wcum = wcum + ww;
        wicum = wicum + ww * xv;
        float d = fminf(fmaxf(wcum - 1.0f, 1e-10f), 1e10f);
        float q = wicum / d;
        float cand = (wcum < 1.0f || q < xv || q > xl) ? MAX_SPIKE : q;
        best = fminf(best, cand);
        xprev = xl;
    }
    bestsh[wave][lane] = best;
    __syncthreads();
    if (tid < 64) {
        float r0 = fminf(fminf(bestsh[0][tid], bestsh[1][tid]),
                         fminf(bestsh[2][tid], bestsh[3][tid]));
        out[b * MOUT + cg * 64 + tid] = r0;
    }
}

extern "C" void kernel_launch(void* const* d_in, const int* in_sizes, int n_in,
                              void* d_out, int out_size, void* d_ws, size_t ws_size,
                              hipStream_t stream) {
    (void)in_sizes; (void)n_in; (void)out_size;
    const float* x = (const float*)d_in[0];
    const float* w = (const float*)d_in[1];
    float* out = (float*)d_out;

    const size_t xs_bytes = (size_t)BATCH * ROWS * sizeof(float);  // 540672
    const size_t ro_bytes = (size_t)BATCH * ROWS * sizeof(int);    // 540672

    if (ws_size >= xs_bytes + ro_bytes) {
        float* xs_g = (float*)d_ws;
        int*   ro_g = (int*)((char*)d_ws + xs_bytes);
        hipLaunchKernelGGL(snn_sort_kernel, dim3(BATCH), dim3(ST), 0, stream,
                           x, xs_g, ro_g);
        hipLaunchKernelGGL(snn_scan_kernel, dim3(BATCH * 8), dim3(128),
                           0, stream, w, xs_g, ro_g, out);
    } else {
        hipLaunchKernelGGL(snn_fc_fused, dim3(BATCH * 8), dim3(256),
                           0, stream, x, w, out);
    }
}

// Round 12
// 61.138 us; speedup vs baseline: 1.3817x; 1.3817x over previous
//
#include <hip/hip_runtime.h>

#define MAX_SPIKE 100000.0f

constexpr int BATCH  = 128;
constexpr int NIN    = 1024;
constexpr int MOUT   = 512;
constexpr int NWAVE  = 4;             // n-segments per block
constexpr int SEGLEN = NIN / NWAVE;   // 256
constexpr int T      = 256;           // 4 waves per block
constexpr int CPB    = 128;           // columns per block (2 per lane)
constexpr int CH     = 8;             // chunk = 8 elements
constexpr int ST     = 512;           // sort threads (8 waves)
constexpr int XSROW  = 1028;          // padded xs row stride (16B-aligned rows)

typedef unsigned long long u64;

__device__ __forceinline__ float fastrcp(float x) {
#if __has_builtin(__builtin_amdgcn_rcpf)
    return __builtin_amdgcn_rcpf(x);   // v_rcp_f32, 1 ulp
#else
    float r; asm volatile("v_rcp_f32 %0, %1" : "=v"(r) : "v"(x)); return r;
#endif
}

// ---------------- kernel 1: per-row stable argsort (hybrid bitonic) --------
// j<=32 stages: __shfl_xor (no barriers). j==64: intra-thread. j>=128: LDS.
__global__ __launch_bounds__(ST) void snn_sort_kernel(const float* __restrict__ x,
                                                      float* __restrict__ xs_g,
                                                      int* __restrict__ ro_g) {
    __shared__ u64 keys[NIN];
    const int tid = threadIdx.x;
    const int b   = blockIdx.x;
    const int wv  = tid >> 6;
    const int l   = tid & 63;
    const int i0  = wv * 128 + l;     // bit6 == 0 always
    const int i1  = i0 + 64;

    // key = (float_bits << 32) | index: x >= 0 so uint order == float order;
    // index low bits make keys distinct -> deterministic == stable argsort.
    u64 e0 = ((u64)__float_as_uint(x[b * NIN + i0]) << 32) | (unsigned)i0;
    u64 e1 = ((u64)__float_as_uint(x[b * NIN + i1]) << 32) | (unsigned)i1;

    auto CE_SHFL = [&](u64& e, int idx, int k, int j) {
        u64 p = __shfl_xor(e, j, 64);
        bool lower   = ((l & j) == 0);
        bool asc     = ((idx & k) == 0);
        bool takeMin = (lower == asc);
        bool pLess   = (p < e);
        e = (pLess == takeMin) ? p : e;
    };
    auto CE_J64 = [&](int k) {
        bool asc = ((i0 & k) == 0);
        bool sw  = asc ? (e0 > e1) : (e0 < e1);
        if (sw) { u64 t = e0; e0 = e1; e1 = t; }
    };

    for (int k = 2; k <= 64; k <<= 1)
        for (int j = k >> 1; j >= 1; j >>= 1) { CE_SHFL(e0, i0, k, j); CE_SHFL(e1, i1, k, j); }
    CE_J64(128);
    for (int j = 32; j >= 1; j >>= 1) { CE_SHFL(e0, i0, 128, j); CE_SHFL(e1, i1, 128, j); }

    for (int k = 256; k <= NIN; k <<= 1) {
        keys[i0] = e0; keys[i1] = e1;
        __syncthreads();
        for (int j = k >> 1; j >= 128; j >>= 1) {
            int idx  = ((tid & ~(j - 1)) << 1) | (tid & (j - 1));
            int part = idx | j;
            u64 a = keys[idx], c = keys[part];
            bool asc = ((idx & k) == 0);
            if (asc ? (a > c) : (a < c)) { keys[idx] = c; keys[part] = a; }
            __syncthreads();
        }
        e0 = keys[i0]; e1 = keys[i1];
        CE_J64(k);
        for (int j = 32; j >= 1; j >>= 1) { CE_SHFL(e0, i0, k, j); CE_SHFL(e1, i1, k, j); }
    }

    xs_g[b * XSROW + i0] = __uint_as_float((unsigned)(e0 >> 32));
    xs_g[b * XSROW + i1] = __uint_as_float((unsigned)(e1 >> 32));
    ro_g[b * NIN + i0] = (int)(unsigned)(e0 & 0xFFFFFFFFull) * (MOUT * 4);  // byte off
    ro_g[b * NIN + i1] = (int)(unsigned)(e1 & 0xFFFFFFFFull) * (MOUT * 4);
    if (tid == 0) xs_g[b * XSROW + NIN] = MAX_SPIKE;
}

// ---------------- kernel 2: NW4 scan, 2 cols/thread, rcp screen ------------
// Relaxed-exactness (bf16-invisible): fmaf cumsum + v_rcp_f32 quotient.
// Candidate-boundary flips are self-compensating (t(n)=xs[n+1] => t(n+1)=t(n)),
// wcum~1 region self-rejects (q huge), wcum>=1 kept explicitly (kills the
// xv=0 ^ wicum=0 spurious-zero edge). Branchless screen ~9 ops/elem/col.
__global__ __launch_bounds__(T) void snn_scan_kernel(const float* __restrict__ w,
                                                     const float* __restrict__ xs_g,
                                                     const int* __restrict__ ro_g,
                                                     float* __restrict__ out) {
    __shared__ float4 xs4[NIN / 4 + 2];   // [256].x = MAX_SPIKE sentinel
    __shared__ int4   ro4[NIN / 4];
    __shared__ float  bestsh[NWAVE][CPB];

    const int tid  = threadIdx.x;
    const int b    = blockIdx.x >> 2;
    const int cg   = blockIdx.x & 3;
    const int wave = tid >> 6;
    const int lane = tid & 63;
    const int seg  = (wave + blockIdx.x) & (NWAVE - 1);   // straggler swizzle
    const unsigned mo4 = (unsigned)(cg * CPB + lane) * 4u;  // col0; col1 = +256B

    {
        const float4* __restrict__ xsrc = (const float4*)(xs_g + (size_t)b * XSROW);
        for (int i = tid; i < NIN / 4 + 1; i += T) xs4[i] = xsrc[i];
        const int4* __restrict__ rsrc = (const int4*)(ro_g + (size_t)b * NIN);
        for (int i = tid; i < NIN / 4; i += T) ro4[i] = rsrc[i];
    }
    __syncthreads();

    const char* wb = (const char*)w;
    float wc0 = 0.0f, wi0 = 0.0f, best0 = MAX_SPIKE;
    float wc1 = 0.0f, wi1 = 0.0f, best1 = MAX_SPIKE;
    float XA[CH], XB[CH], A0[CH], A1[CH], B0[CH], B1[CH];

// read xs chunk (2x ds_read_b128) + 16 weight loads (2 cols x 8 elems)
#define RDIS(X, V0, V1, c_) { const int cc_ = (c_); \
    float4 a0_ = xs4[cc_ * 2], a1_ = xs4[cc_ * 2 + 1]; \
    X[0] = a0_.x; X[1] = a0_.y; X[2] = a0_.z; X[3] = a0_.w; \
    X[4] = a1_.x; X[5] = a1_.y; X[6] = a1_.z; X[7] = a1_.w; \
    int4 r0_ = ro4[cc_ * 2], r1_ = ro4[cc_ * 2 + 1]; \
    V0[0] = *(const float*)(wb + ((unsigned)r0_.x + mo4)); \
    V1[0] = *(const float*)(wb + ((unsigned)r0_.x + mo4 + 256u)); \
    V0[1] = *(const float*)(wb + ((unsigned)r0_.y + mo4)); \
    V1[1] = *(const float*)(wb + ((unsigned)r0_.y + mo4 + 256u)); \
    V0[2] = *(const float*)(wb + ((unsigned)r0_.z + mo4)); \
    V1[2] = *(const float*)(wb + ((unsigned)r0_.z + mo4 + 256u)); \
    V0[3] = *(const float*)(wb + ((unsigned)r0_.w + mo4)); \
    V1[3] = *(const float*)(wb + ((unsigned)r0_.w + mo4 + 256u)); \
    V0[4] = *(const float*)(wb + ((unsigned)r1_.x + mo4)); \
    V1[4] = *(const float*)(wb + ((unsigned)r1_.x + mo4 + 256u)); \
    V0[5] = *(const float*)(wb + ((unsigned)r1_.y + mo4)); \
    V1[5] = *(const float*)(wb + ((unsigned)r1_.y + mo4 + 256u)); \
    V0[6] = *(const float*)(wb + ((unsigned)r1_.z + mo4)); \
    V1[6] = *(const float*)(wb + ((unsigned)r1_.z + mo4 + 256u)); \
    V0[7] = *(const float*)(wb + ((unsigned)r1_.w + mo4)); \
    V1[7] = *(const float*)(wb + ((unsigned)r1_.w + mo4 + 256u)); }

#define CHEAP8(X, V0, V1) { _Pragma("unroll") \
    for (int u = 0; u < CH; ++u) { \
        float xv = X[u]; \
        float w0 = V0[u], w1 = V1[u]; \
        wc0 += w0; wi0 = fmaf(w0, xv, wi0); \
        wc1 += w1; wi1 = fmaf(w1, xv, wi1); } }

    // Branchless screen per col: d=max(wcum-1,1e-10); q=wicum*rcp(d);
    // ok = wcum>=1 && q in [xv,xl]; best = ok ? min(best,q) : best.
#define SCREEN8(X, V0, V1, XL8) { _Pragma("unroll") \
    for (int u = 0; u < CH; ++u) { \
        float xv = X[u]; \
        float xl = (u < CH - 1) ? X[u + 1] : (XL8); \
        float w0 = V0[u], w1 = V1[u]; \
        wc0 += w0; wi0 = fmaf(w0, xv, wi0); \
        wc1 += w1; wi1 = fmaf(w1, xv, wi1); \
        float d0 = fmaxf(wc0 - 1.0f, 1e-10f); \
        float d1 = fmaxf(wc1 - 1.0f, 1e-10f); \
        float q0 = wi0 * fastrcp(d0); \
        float q1 = wi1 * fastrcp(d1); \
        bool ok0 = (wc0 >= 1.0f) && (q0 >= xv) && (q0 <= xl); \
        bool ok1 = (wc1 >= 1.0f) && (q1 >= xv) && (q1 <= xl); \
        best0 = ok0 ? fminf(best0, q0) : best0; \
        best1 = ok1 ? fminf(best1, q1) : best1; } }

    // Cheap mode while ALL lanes/cols have wcum < 1 (weights >= 0 -> monotone
    // -> no candidate possible: q=wi*1e10 huge -> rejected anyway). Crossing
    // chunk REPLAYED from a 4-register snapshot (identical op order).
#define PROC8(X, V0, V1, XL8) { \
    if (!scr) { \
        float c0_ = wc0, i0_ = wi0, c1_ = wc1, i1_ = wi1; \
        CHEAP8(X, V0, V1); \
        if (__any((int)((wc0 >= 1.0f) || (wc1 >= 1.0f)))) { \
            wc0 = c0_; wi0 = i0_; wc1 = c1_; wi1 = i1_; scr = true; } \
    } \
    if (scr) { SCREEN8(X, V0, V1, XL8); } }

    const int s0   = seg * (SEGLEN / CH);   // 0,32,64,96
    const int cend = s0 + SEGLEN / CH;

    // ---- phase 1: shared exact-order prefix (identical fma order across
    // waves -> consistent segment handoff); no screening by construction.
    if (s0 > 0) {
        RDIS(XA, A0, A1, 0);
        for (int c = 0; c < s0; c += 2) {
            RDIS(XB, B0, B1, c + 1);
            CHEAP8(XA, A0, A1);
            if (c + 2 < s0) RDIS(XA, A0, A1, c + 2);
            CHEAP8(XB, B0, B1);
        }
    }

    // ---- phase 2: screened scan on own segment.
    bool scr = (__any((int)((wc0 >= 1.0f) || (wc1 >= 1.0f))) != 0);

    RDIS(XA, A0, A1, s0);
    for (int c = s0; c < cend; c += 2) {
        RDIS(XB, B0, B1, c + 1);
        PROC8(XA, A0, A1, XB[0]);
        const bool more = (c + 2 < cend);
        if (more) RDIS(XA, A0, A1, c + 2);
        float xlB = more ? XA[0] : xs4[(c + 2) * 2].x;  // sentinel-safe
        PROC8(XB, B0, B1, xlB);
    }
#undef PROC8
#undef SCREEN8
#undef CHEAP8
#undef RDIS

    bestsh[seg][lane]      = best0;
    bestsh[seg][lane + 64] = best1;
    __syncthreads();
    if (tid < CPB) {
        float r0 = fminf(fminf(bestsh[0][tid], bestsh[1][tid]),
                         fminf(bestsh[2][tid], bestsh[3][tid]));
        out[b * MOUT + cg * CPB + tid] = r0;
    }
}

// ---------------- fallback: fused kernel (if ws too small) -----------------
__global__ __launch_bounds__(256) void snn_fc_fused(const float* __restrict__ x,
                                                    const float* __restrict__ w,
                                                    float* __restrict__ out) {
    #pragma clang fp contract(off)
    __shared__ u64 keys[NIN];
    __shared__ float xs[NIN + 1];
    __shared__ int   roff[NIN];
    __shared__ float bestsh[4][64];

    const int tid  = threadIdx.x;
    const int b    = blockIdx.x >> 3;
    const int cg   = blockIdx.x & 7;
    const int wave = tid >> 6;
    const int lane = tid & 63;
    const int mo   = cg * 64 + lane;

    for (int i = tid; i < NIN; i += 256) {
        unsigned int bits = __float_as_uint(x[b * NIN + i]);
        keys[i] = ((u64)bits << 32) | (unsigned int)i;
    }
    __syncthreads();
    for (int k = 2; k <= NIN; k <<= 1)
        for (int j = k >> 1; j > 0; j >>= 1) {
            #pragma unroll
            for (int r = 0; r < NIN / 256; ++r) {
                int i = tid + r * 256, ixj = i ^ j;
                if (ixj > i) {
                    u64 a = keys[i], c2 = keys[ixj];
                    bool asc = ((i & k) == 0);
                    if ((a > c2) == asc) { keys[i] = c2; keys[ixj] = a; }
                }
            }
            __syncthreads();
        }
    for (int i = tid; i < NIN; i += 256) {
        u64 kk = keys[i];
        xs[i]   = __uint_as_float((unsigned int)(kk >> 32));
        roff[i] = (int)(kk & 0xFFFFFFFFull) * MOUT;
    }
    if (tid == 0) xs[NIN] = MAX_SPIKE;
    __syncthreads();

    const float* __restrict__ wcol = w + mo;
    float wcum = 0.0f, wicum = 0.0f, best = MAX_SPIKE;

    for (int n = 0; n < wave * 256; ++n) {
        float ww = wcol[roff[n]];
        wcum = wcum + ww;
        wicum = wicum + ww * xs[n];
    }
    const int n0 = wave * 256;
    float xprev = xs[n0];
    for (int n = n0; n < n0 + 256; ++n) {
        float ww = wcol[roff[n]];
        float xv = xprev, xl = xs[n + 1];
        wcum = wcum + ww;
        wicum = wicum + ww * xv;
        float d = fminf(fmaxf(wcum - 1.0f, 1e-10f), 1e10f);
        float q = wicum / d;
        float cand = (wcum < 1.0f || q < xv || q > xl) ? MAX_SPIKE : q;
        best = fminf(best, cand);
        xprev = xl;
    }
    bestsh[wave][lane] = best;
    __syncthreads();
    if (tid < 64) {
        float r0 = fminf(fminf(bestsh[0][tid], bestsh[1][tid]),
                         fminf(bestsh[2][tid], bestsh[3][tid]));
        out[b * MOUT + cg * 64 + tid] = r0;
    }
}

extern "C" void kernel_launch(void* const* d_in, const int* in_sizes, int n_in,
                              void* d_out, int out_size, void* d_ws, size_t ws_size,
                              hipStream_t stream) {
    (void)in_sizes; (void)n_in; (void)out_size;
    const float* x = (const float*)d_in[0];
    const float* w = (const float*)d_in[1];
    float* out = (float*)d_out;

    const size_t xs_bytes = (size_t)BATCH * XSROW * sizeof(float);  // 526336
    const size_t ro_bytes = (size_t)BATCH * NIN * sizeof(int);      // 524288

    if (ws_size >= xs_bytes + ro_bytes) {
        float* xs_g = (float*)d_ws;
        int*   ro_g = (int*)((char*)d_ws + xs_bytes);
        hipLaunchKernelGGL(snn_sort_kernel, dim3(BATCH), dim3(ST), 0, stream,
                           x, xs_g, ro_g);
        hipLaunchKernelGGL(snn_scan_kernel, dim3(BATCH * (MOUT / CPB)), dim3(T),
                           0, stream, w, xs_g, ro_g, out);
    } else {
        hipLaunchKernelGGL(snn_fc_fused, dim3(BATCH * 8), dim3(256),
                           0, stream, x, w, out);
    }
}

// Round 13
// 34.042 us; speedup vs baseline: 2.4814x; 1.7959x over previous
//
#include <hip/hip_runtime.h>

#define MAX_SPIKE 100000.0f

constexpr int BATCH  = 128;
constexpr int NIN    = 1024;
constexpr int MOUT   = 512;
constexpr int NSEG   = 8;             // segments == waves per block
constexpr int SEGLEN = NIN / NSEG;    // 128
constexpr int T      = 512;           // 8 waves
constexpr int CPB    = 64;            // columns per block (1 per lane)
constexpr int CH     = 8;             // chunk = 8 elements
constexpr int ST     = 512;           // sort threads
constexpr int XSROW  = 1028;          // padded xs row stride

typedef unsigned long long u64;

__device__ __forceinline__ float fastrcp(float x) {
#if __has_builtin(__builtin_amdgcn_rcpf)
    return __builtin_amdgcn_rcpf(x);   // v_rcp_f32, 1 ulp
#else
    float r; asm volatile("v_rcp_f32 %0, %1" : "=v"(r) : "v"(x)); return r;
#endif
}

// ---------------- kernel 1: per-row stable argsort (hybrid bitonic) --------
__global__ __launch_bounds__(ST) void snn_sort_kernel(const float* __restrict__ x,
                                                      float* __restrict__ xs_g,
                                                      int* __restrict__ ro_g) {
    __shared__ u64 keys[NIN];
    const int tid = threadIdx.x;
    const int b   = blockIdx.x;
    const int wv  = tid >> 6;
    const int l   = tid & 63;
    const int i0  = wv * 128 + l;     // bit6 == 0 always
    const int i1  = i0 + 64;

    // key = (float_bits << 32) | index: x >= 0 so uint order == float order;
    // index low bits make keys distinct -> deterministic == stable argsort.
    u64 e0 = ((u64)__float_as_uint(x[b * NIN + i0]) << 32) | (unsigned)i0;
    u64 e1 = ((u64)__float_as_uint(x[b * NIN + i1]) << 32) | (unsigned)i1;

    auto CE_SHFL = [&](u64& e, int idx, int k, int j) {
        u64 p = __shfl_xor(e, j, 64);
        bool lower   = ((l & j) == 0);
        bool asc     = ((idx & k) == 0);
        bool takeMin = (lower == asc);
        bool pLess   = (p < e);
        e = (pLess == takeMin) ? p : e;
    };
    auto CE_J64 = [&](int k) {
        bool asc = ((i0 & k) == 0);
        bool sw  = asc ? (e0 > e1) : (e0 < e1);
        if (sw) { u64 t = e0; e0 = e1; e1 = t; }
    };

    for (int k = 2; k <= 64; k <<= 1)
        for (int j = k >> 1; j >= 1; j >>= 1) { CE_SHFL(e0, i0, k, j); CE_SHFL(e1, i1, k, j); }
    CE_J64(128);
    for (int j = 32; j >= 1; j >>= 1) { CE_SHFL(e0, i0, 128, j); CE_SHFL(e1, i1, 128, j); }

    for (int k = 256; k <= NIN; k <<= 1) {
        keys[i0] = e0; keys[i1] = e1;
        __syncthreads();
        for (int j = k >> 1; j >= 128; j >>= 1) {
            int idx  = ((tid & ~(j - 1)) << 1) | (tid & (j - 1));
            int part = idx | j;
            u64 a = keys[idx], c = keys[part];
            bool asc = ((idx & k) == 0);
            if (asc ? (a > c) : (a < c)) { keys[idx] = c; keys[part] = a; }
            __syncthreads();
        }
        e0 = keys[i0]; e1 = keys[i1];
        CE_J64(k);
        for (int j = 32; j >= 1; j >>= 1) { CE_SHFL(e0, i0, k, j); CE_SHFL(e1, i1, k, j); }
    }

    xs_g[b * XSROW + i0] = __uint_as_float((unsigned)(e0 >> 32));
    xs_g[b * XSROW + i1] = __uint_as_float((unsigned)(e1 >> 32));
    ro_g[b * NIN + i0] = (int)(unsigned)(e0 & 0xFFFFFFFFull) * (MOUT * 4);  // byte off
    ro_g[b * NIN + i1] = (int)(unsigned)(e1 & 0xFFFFFFFFull) * (MOUT * 4);
    if (tid == 0) xs_g[b * XSROW + NIN] = MAX_SPIKE;
}

// ---------------- kernel 2: two-pass zero-redundancy scan ------------------
// Pass 1: wave s cheap-scans ONLY its 128 elements -> partial (pc,pi) in LDS.
// Barrier. base(s) = sum of partials t<s (O(1e-6) reassociation vs reference,
// bf16-invisible by the boundary-compensation identity, validated r12).
// Pass 2: screen own segment from base, with two provable segment skips:
//   pre:  end-wcum < 1      -> wcum<1 throughout -> no candidate possible.
//   post: q_base < xs[n0]*(1-1e-3) -> q stays below every window forever
//         (q' in (q, xs[n+1]) whenever q < xs[n+1]); margin makes borderline
//         segments screen, preserving the compensation chain.
__global__ __launch_bounds__(T, 8) void snn_scan_kernel(const float* __restrict__ w,
                                                        const float* __restrict__ xs_g,
                                                        const int* __restrict__ ro_g,
                                                        float* __restrict__ out) {
    __shared__ float4 xs4[NIN / 4 + 2];   // [256].x = MAX_SPIKE sentinel
    __shared__ int4   ro4[NIN / 4];
    __shared__ float2 partsh[NSEG][CPB];  // per-segment (wcum, wicum) partials
    __shared__ float  bestsh[NSEG][CPB];

    const int tid  = threadIdx.x;
    const int b    = blockIdx.x >> 3;
    const int cg   = blockIdx.x & 7;
    const int seg  = tid >> 6;            // wave == segment (uniform work)
    const int lane = tid & 63;
    const unsigned mo4 = (unsigned)(cg * CPB + lane) * 4u;

    {
        const float4* __restrict__ xsrc = (const float4*)(xs_g + (size_t)b * XSROW);
        for (int i = tid; i < NIN / 4 + 1; i += T) xs4[i] = xsrc[i];
        const int4* __restrict__ rsrc = (const int4*)(ro_g + (size_t)b * NIN);
        for (int i = tid; i < NIN / 4; i += T) ro4[i] = rsrc[i];
    }
    __syncthreads();

    const char* wb = (const char*)w;
    float XA[CH], XB[CH], WA[CH], WB[CH];

// read xs chunk (2x ds_read_b128) + 8 weight loads
#define RDIS(X, W, c_) { const int cc_ = (c_); \
    float4 a0_ = xs4[cc_ * 2], a1_ = xs4[cc_ * 2 + 1]; \
    X[0] = a0_.x; X[1] = a0_.y; X[2] = a0_.z; X[3] = a0_.w; \
    X[4] = a1_.x; X[5] = a1_.y; X[6] = a1_.z; X[7] = a1_.w; \
    int4 r0_ = ro4[cc_ * 2], r1_ = ro4[cc_ * 2 + 1]; \
    W[0] = *(const float*)(wb + ((unsigned)r0_.x + mo4)); \
    W[1] = *(const float*)(wb + ((unsigned)r0_.y + mo4)); \
    W[2] = *(const float*)(wb + ((unsigned)r0_.z + mo4)); \
    W[3] = *(const float*)(wb + ((unsigned)r0_.w + mo4)); \
    W[4] = *(const float*)(wb + ((unsigned)r1_.x + mo4)); \
    W[5] = *(const float*)(wb + ((unsigned)r1_.y + mo4)); \
    W[6] = *(const float*)(wb + ((unsigned)r1_.z + mo4)); \
    W[7] = *(const float*)(wb + ((unsigned)r1_.w + mo4)); }

    const int c0 = seg * (SEGLEN / CH);   // seg*16
    const int c1 = c0 + SEGLEN / CH;      // +16 (even span)

    // ---- pass 1: cheap partial over own segment only
    float pc = 0.0f, pi = 0.0f;
#define CHEAP8(X, W) { _Pragma("unroll") \
    for (int u = 0; u < CH; ++u) { \
        float ww = W[u]; \
        pc += ww; pi = fmaf(ww, X[u], pi); } }

    RDIS(XA, WA, c0);
    for (int c = c0; c < c1; c += 2) {
        RDIS(XB, WB, c + 1);
        CHEAP8(XA, WA);
        if (c + 2 < c1) RDIS(XA, WA, c + 2);
        CHEAP8(XB, WB);
    }
#undef CHEAP8

    partsh[seg][lane] = make_float2(pc, pi);
    __syncthreads();

    // ---- base = ascending sum of earlier segments' partials
    float bc = 0.0f, bi = 0.0f;
    for (int t = 0; t < seg; ++t) {
        float2 p = partsh[t][lane];
        bc += p.x; bi += p.y;
    }

    float best = MAX_SPIKE;
    {
        const float xn0  = xs4[c0 * 2].x;            // xs[seg*128]
        const float endc = bc + pc;
        bool pre  = (endc < 1.0f);
        bool post = (bc > 1.0f) && (bi < (xn0 * (bc - 1.0f)) * (1.0f - 1e-3f));
        bool skip = (__all((int)(pre || post)) != 0);

        if (!skip) {
            float wc = bc, wi = bi;
            // Branchless screen: d=max(wc-1,1e-10); q=wi*rcp(d) (1 ulp);
            // ok = wc>=1 && q in [xv,xl]  (wc>=1 kills the xv=0^wi=0 edge).
#define SCREEN8(X, W, XL8) { _Pragma("unroll") \
    for (int u = 0; u < CH; ++u) { \
        float xv = X[u]; \
        float xl = (u < CH - 1) ? X[u + 1] : (XL8); \
        float ww = W[u]; \
        wc += ww; wi = fmaf(ww, xv, wi); \
        float d = fmaxf(wc - 1.0f, 1e-10f); \
        float q = wi * fastrcp(d); \
        bool ok = (wc >= 1.0f) && (q >= xv) && (q <= xl); \
        best = ok ? fminf(best, q) : best; } }

            RDIS(XA, WA, c0);
            for (int c = c0; c < c1; c += 2) {
                RDIS(XB, WB, c + 1);
                SCREEN8(XA, WA, XB[0]);
                const bool more = (c + 2 < c1);
                if (more) RDIS(XA, WA, c + 2);
                float xlB = more ? XA[0] : xs4[(c + 2) * 2].x;  // sentinel-safe
                SCREEN8(XB, WB, xlB);
            }
#undef SCREEN8
        }
    }
#undef RDIS

    bestsh[seg][lane] = best;
    __syncthreads();
    if (tid < CPB) {
        float r = bestsh[0][tid];
        #pragma unroll
        for (int s = 1; s < NSEG; ++s) r = fminf(r, bestsh[s][tid]);
        out[b * MOUT + cg * CPB + tid] = r;
    }
}

// ---------------- fallback: fused kernel (if ws too small) -----------------
__global__ __launch_bounds__(256) void snn_fc_fused(const float* __restrict__ x,
                                                    const float* __restrict__ w,
                                                    float* __restrict__ out) {
    #pragma clang fp contract(off)
    __shared__ u64 keys[NIN];
    __shared__ float xs[NIN + 1];
    __shared__ int   roff[NIN];
    __shared__ float bestsh[4][64];

    const int tid  = threadIdx.x;
    const int b    = blockIdx.x >> 3;
    const int cg   = blockIdx.x & 7;
    const int wave = tid >> 6;
    const int lane = tid & 63;
    const int mo   = cg * 64 + lane;

    for (int i = tid; i < NIN; i += 256) {
        unsigned int bits = __float_as_uint(x[b * NIN + i]);
        keys[i] = ((u64)bits << 32) | (unsigned int)i;
    }
    __syncthreads();
    for (int k = 2; k <= NIN; k <<= 1)
        for (int j = k >> 1; j > 0; j >>= 1) {
            #pragma unroll
            for (int r = 0; r < NIN / 256; ++r) {
                int i = tid + r * 256, ixj = i ^ j;
                if (ixj > i) {
                    u64 a = keys[i], c2 = keys[ixj];
                    bool asc = ((i & k) == 0);
                    if ((a > c2) == asc) { keys[i] = c2; keys[ixj] = a; }
                }
            }
            __syncthreads();
        }
    for (int i = tid; i < NIN; i += 256) {
        u64 kk = keys[i];
        xs[i]   = __uint_as_float((unsigned int)(kk >> 32));
        roff[i] = (int)(kk & 0xFFFFFFFFull) * MOUT;
    }
    if (tid == 0) xs[NIN] = MAX_SPIKE;
    __syncthreads();

    const float* __restrict__ wcol = w + mo;
    float wcum = 0.0f, wicum = 0.0f, best = MAX_SPIKE;

    for (int n = 0; n < wave * 256; ++n) {
        float ww = wcol[roff[n]];
        wcum = wcum + ww;
        wicum = wicum + ww * xs[n];
    }
    const int n0 = wave * 256;
    float xprev = xs[n0];
    for (int n = n0; n < n0 + 256; ++n) {
        float ww = wcol[roff[n]];
        float xv = xprev, xl = xs[n + 1];
        wcum = wcum + ww;
        wicum = wicum + ww * xv;
        float d = fminf(fmaxf(wcum - 1.0f, 1e-10f), 1e10f);
        float q = wicum / d;
        float cand = (wcum < 1.0f || q < xv || q > xl) ? MAX_SPIKE : q;
        best = fminf(best, cand);
        xprev = xl;
    }
    bestsh[wave][lane] = best;
    __syncthreads();
    if (tid < 64) {
        float r0 = fminf(fminf(bestsh[0][tid], bestsh[1][tid]),
                         fminf(bestsh[2][tid], bestsh[3][tid]));
        out[b * MOUT + cg * 64 + tid] = r0;
    }
}

extern "C" void kernel_launch(void* const* d_in, const int* in_sizes, int n_in,
                              void* d_out, int out_size, void* d_ws, size_t ws_size,
                              hipStream_t stream) {
    (void)in_sizes; (void)n_in; (void)out_size;
    const float* x = (const float*)d_in[0];
    const float* w = (const float*)d_in[1];
    float* out = (float*)d_out;

    const size_t xs_bytes = (size_t)BATCH * XSROW * sizeof(float);  // 526336
    const size_t ro_bytes = (size_t)BATCH * NIN * sizeof(int);      // 524288

    if (ws_size >= xs_bytes + ro_bytes) {
        float* xs_g = (float*)d_ws;
        int*   ro_g = (int*)((char*)d_ws + xs_bytes);
        hipLaunchKernelGGL(snn_sort_kernel, dim3(BATCH), dim3(ST), 0, stream,
                           x, xs_g, ro_g);
        hipLaunchKernelGGL(snn_scan_kernel, dim3(BATCH * (MOUT / CPB)), dim3(T),
                           0, stream, w, xs_g, ro_g, out);
    } else {
        hipLaunchKernelGGL(snn_fc_fused, dim3(BATCH * 8), dim3(256),
                           0, stream, x, w, out);
    }
}